// Round 5
// baseline (1966.984 us; speedup 1.0000x reference)
//
#include <hip/hip_runtime.h>

typedef unsigned short u16;
typedef unsigned int u32;
typedef __attribute__((ext_vector_type(8))) short short8;
typedef __attribute__((ext_vector_type(4))) float f4;

#define DEV static __device__ __forceinline__

constexpr int BB = 16, NN = 2048, DD = 1024, HH = 8, DHD = 64, II = 512, LL = 64, DEPTHC = 6, FFC = 4096;

DEV u16 f2bf(float f) {
  union { float f; u32 u; } v; v.f = f;
  u32 r = v.u + 0x7FFFu + ((v.u >> 16) & 1u);
  return (u16)(r >> 16);
}

DEV void pack8(const float* v, u16* dst) {
  union { u16 u[8]; int4 i; } p;
  #pragma unroll
  for (int e = 0; e < 8; e++) p.u[e] = f2bf(v[e]);
  *(int4*)dst = p.i;
}

typedef const u32 __attribute__((address_space(1)))* gas_p;
typedef u32 __attribute__((address_space(3)))* las_p;
DEV void gl_lds16(const void* g, void* l) {
  __builtin_amdgcn_global_load_lds((gas_p)g, (las_p)l, 16, 0, 0);
}

// ---------------- pre0: maskscan (16) + lat init (1024) + zero biases (39) ----------------
__global__ __launch_bounds__(256) void pre0_k(const int* __restrict__ mask,
    int* __restrict__ idx, int* __restrict__ cnt,
    const float* __restrict__ latents, float* __restrict__ lat,
    float* __restrict__ biasall, int nbias) {
  int bid = blockIdx.x, tid = threadIdx.x;
  if (bid < 16) {
    int b = bid;
    int lane = tid & 63, wv = tid >> 6;
    const int* mrow = mask + (size_t)b * NN;
    int base = tid * 8;
    int keep[8]; int local = 0;
    #pragma unroll
    for (int j = 0; j < 8; j++) { keep[j] = (mrow[base + j] == 0); local += keep[j]; }
    int incl = local;
    #pragma unroll
    for (int off = 1; off < 64; off <<= 1) {
      int v = __shfl_up(incl, off, 64);
      if (lane >= off) incl += v;
    }
    __shared__ int wsum[4];
    if (lane == 63) wsum[wv] = incl;
    __syncthreads();
    int wbase = 0;
    for (int w = 0; w < wv; w++) wbase += wsum[w];
    int pos = wbase + incl - local;
    #pragma unroll
    for (int j = 0; j < 8; j++) if (keep[j]) idx[(size_t)b * NN + pos++] = base + j;
    if (tid == 255) cnt[b] = wbase + incl;
  } else if (bid < 16 + 1024) {
    int i = (bid - 16) * 256 + tid;
    ((float4*)lat)[i] = ((const float4*)latents)[i & (LL * DD / 4 - 1)];
  } else {
    int i = ((bid - 1040) * 256 + tid) * 4;
    if (i < nbias) *(float4*)(biasall + i) = float4{0.f, 0.f, 0.f, 0.f};
  }
}

// ---------------- fused LN + gather: xcomp[b][j] = LN(x[b][idx[b][j]]); pad rows zeroed ----------------
__global__ __launch_bounds__(256) void ln_gather_k(const float* __restrict__ x,
    const int* __restrict__ idx, const int* __restrict__ cnt, u16* __restrict__ xcomp) {
  int b = blockIdx.y, j = blockIdx.x, tid = threadIdx.x;
  int c = cnt[b];
  if (j >= ((c + 127) & ~127)) return;
  ushort4* orow = (ushort4*)(xcomp + ((size_t)b * NN + j) * DD);
  if (j >= c) { orow[tid] = make_ushort4(0, 0, 0, 0); return; }
  int src = idx[(size_t)b * NN + j];
  const float4* rp = (const float4*)(x + ((size_t)b * NN + src) * DD);
  float4 v = rp[tid];
  float s = v.x + v.y + v.z + v.w;
  float s2 = v.x*v.x + v.y*v.y + v.z*v.z + v.w*v.w;
  #pragma unroll
  for (int off = 32; off >= 1; off >>= 1) {
    s  += __shfl_xor(s, off, 64);
    s2 += __shfl_xor(s2, off, 64);
  }
  __shared__ float red[8];
  int wv = tid >> 6;
  if ((tid & 63) == 0) { red[wv] = s; red[4 + wv] = s2; }
  __syncthreads();
  s  = red[0] + red[1] + red[2] + red[3];
  s2 = red[4] + red[5] + red[6] + red[7];
  float mu = s * (1.f / DD);
  float var = s2 * (1.f / DD) - mu * mu;
  float rstd = rsqrtf(var + 1e-5f);
  orow[tid] = make_ushort4(f2bf((v.x - mu) * rstd), f2bf((v.y - mu) * rstd),
                           f2bf((v.z - mu) * rstd), f2bf((v.w - mu) * rstd));
}

// ---------------- final LayerNorm ----------------
__global__ __launch_bounds__(256) void ln_final_k(const float* __restrict__ in,
    const float* __restrict__ w, const float* __restrict__ bias, float* __restrict__ out) {
  int row = blockIdx.x;
  int tid = threadIdx.x;
  const float4* rp = (const float4*)(in + (size_t)row * DD);
  float4 x = rp[tid];
  float s = x.x + x.y + x.z + x.w;
  float s2 = x.x*x.x + x.y*x.y + x.z*x.z + x.w*x.w;
  #pragma unroll
  for (int off = 32; off >= 1; off >>= 1) {
    s  += __shfl_xor(s, off, 64);
    s2 += __shfl_xor(s2, off, 64);
  }
  __shared__ float red[8];
  int wv = tid >> 6;
  if ((tid & 63) == 0) { red[wv] = s; red[4 + wv] = s2; }
  __syncthreads();
  s  = red[0] + red[1] + red[2] + red[3];
  s2 = red[4] + red[5] + red[6] + red[7];
  float mu = s * (1.f / DD);
  float var = s2 * (1.f / DD) - mu * mu;
  float rstd = rsqrtf(var + 1e-5f);
  int col = tid * 4;
  float4 o;
  o.x = (x.x - mu) * rstd * w[col+0] + bias[col+0];
  o.y = (x.y - mu) * rstd * w[col+1] + bias[col+1];
  o.z = (x.z - mu) * rstd * w[col+2] + bias[col+2];
  o.w = (x.w - mu) * rstd * w[col+3] + bias[col+3];
  ((float4*)out)[(size_t)row * (DD/4) + tid] = o;
}

// ---------------- ALL weight transposes (64x64 tiles, coalesced 16B writes) ----------------
// per depth 2560 blocks: [0,128) Wq ; [128,384) Wkv ; [384,512) Wo ; [512,1536) W1 ; [1536,2560) W2
__global__ __launch_bounds__(256) void transpall_k(const float* __restrict__ WqA,
    const float* __restrict__ WkvA, const float* __restrict__ WoA,
    const float* __restrict__ W1A, const float* __restrict__ W2A,
    const float* __restrict__ lnlw, const float* __restrict__ lnlb,
    const float* __restrict__ lnmw, const float* __restrict__ lnmb,
    const float* __restrict__ ffw, const float* __restrict__ ffb,
    u16* __restrict__ WqkvTA, u16* __restrict__ WkvTfA, u16* __restrict__ WoTA,
    u16* __restrict__ W1TA, u16* __restrict__ W2TA, float* __restrict__ biasall) {
  __shared__ float t[64][67];
  __shared__ float sw1[64], sw2[64], sb1[64], sb2[64];
  __shared__ float bred[64][4];
  int gid = blockIdx.x, tid = threadIdx.x;
  int depth = gid / 2560;
  int id = gid % 2560;
  float* biasqkv = biasall + depth * 1536;
  float* biaskv  = biasall + DEPTHC*1536 + depth * 1024;
  float* bias1   = biasall + DEPTHC*1536 + DEPTHC*1024 + depth * 4096;
  const float* in; int R, C, c0, r0;
  u16 *o1, *o2 = nullptr;
  const float *w1v = nullptr, *w2v = nullptr, *b1v = nullptr, *b2v = nullptr;
  float *bo1 = nullptr, *bo2 = nullptr;
  if (id < 128) {
    in = WqA + (size_t)depth*1024*512; R = 1024; C = 512;
    r0 = (id >> 3) * 64; c0 = (id & 7) * 64;
    o1 = WqkvTA + (size_t)depth*1536*1024;
    w1v = lnlw + depth*1024; b1v = lnlb + depth*1024; bo1 = biasqkv;
  } else if (id < 384) {
    int l = id - 128;
    in = WkvA + (size_t)depth*1024*1024; R = 1024; C = 1024;
    r0 = (l >> 4) * 64; c0 = (l & 15) * 64;
    o1 = WqkvTA + (size_t)depth*1536*1024 + (size_t)512*1024;
    w1v = lnlw + depth*1024; b1v = lnlb + depth*1024; bo1 = biasqkv + 512;
    o2 = WkvTfA + (size_t)depth*1024*1024;
    w2v = lnmw + depth*1024; b2v = lnmb + depth*1024; bo2 = biaskv;
  } else if (id < 512) {
    int l = id - 384;
    in = WoA + (size_t)depth*512*1024; R = 512; C = 1024;
    r0 = (l >> 4) * 64; c0 = (l & 15) * 64;
    o1 = WoTA + (size_t)depth*1024*512;
  } else if (id < 1536) {
    int l = id - 512;
    in = W1A + (size_t)depth*1024*4096; R = 1024; C = 4096;
    r0 = (l >> 6) * 64; c0 = (l & 63) * 64;
    o1 = W1TA + (size_t)depth*4096*1024;
    w1v = ffw + depth*1024; b1v = ffb + depth*1024; bo1 = bias1;
  } else {
    int l = id - 1536;
    in = W2A + (size_t)depth*4096*1024; R = 4096; C = 1024;
    r0 = (l >> 4) * 64; c0 = (l & 15) * 64;
    o1 = W2TA + (size_t)depth*1024*4096;
  }
  #pragma unroll
  for (int j = 0; j < 4; j++) {
    int rr = (tid >> 4) + j * 16;
    float4 v = *(const float4*)(in + (size_t)(r0 + rr) * C + c0 + (tid & 15) * 4);
    int cc = (tid & 15) * 4;
    t[rr][cc+0] = v.x; t[rr][cc+1] = v.y; t[rr][cc+2] = v.z; t[rr][cc+3] = v.w;
  }
  if (tid < 64) {
    sw1[tid] = w1v ? w1v[r0 + tid] : 1.f;
    sb1[tid] = b1v ? b1v[r0 + tid] : 0.f;
    sw2[tid] = w2v ? w2v[r0 + tid] : 1.f;
    sb2[tid] = b2v ? b2v[r0 + tid] : 0.f;
  }
  __syncthreads();
  #pragma unroll
  for (int p = 0; p < 2; p++) {
    int ch = p * 256 + tid;
    int oc = ch >> 3;
    int or8 = (ch & 7) * 8;
    float v[8], vv[8];
    #pragma unroll
    for (int e = 0; e < 8; e++) v[e] = t[or8 + e][oc];
    #pragma unroll
    for (int e = 0; e < 8; e++) vv[e] = v[e] * sw1[or8 + e];
    pack8(vv, o1 + (size_t)(c0 + oc) * R + r0 + or8);
    if (o2) {
      #pragma unroll
      for (int e = 0; e < 8; e++) vv[e] = v[e] * sw2[or8 + e];
      pack8(vv, o2 + (size_t)(c0 + oc) * R + r0 + or8);
    }
  }
  if (bo1) {
    int c = tid >> 2, q = tid & 3;
    float a = 0.f;
    #pragma unroll
    for (int i = 0; i < 16; i++) a += sb1[q*16 + i] * t[q*16 + i][c];
    bred[c][q] = a;
    __syncthreads();
    if (tid < 64) atomicAdd(&bo1[c0 + tid], bred[tid][0] + bred[tid][1] + bred[tid][2] + bred[tid][3]);
  }
  if (bo2) {
    __syncthreads();
    int c = tid >> 2, q = tid & 3;
    float a = 0.f;
    #pragma unroll
    for (int i = 0; i < 16; i++) a += sb2[q*16 + i] * t[q*16 + i][c];
    bred[c][q] = a;
    __syncthreads();
    if (tid < 64) atomicAdd(&bo2[c0 + tid], bred[tid][0] + bred[tid][1] + bred[tid][2] + bred[tid][3]);
  }
}

// ---------------- fused GEMM: kv (2048 swizzled, K->kx, V->vxT) + latent qkv (96, LN fused) ----
__global__ __launch_bounds__(256) void gemm_fused_k(
    const u16* __restrict__ xcomp, const u16* __restrict__ WkvTf, const float* __restrict__ biaskv,
    u16* __restrict__ kx, u16* __restrict__ vxT, const int* __restrict__ cnt,
    const float* __restrict__ lat, const u16* __restrict__ WqkvT, const float* __restrict__ biasqkv,
    u16* __restrict__ qk, u16* __restrict__ vlatT) {
  __shared__ __align__(16) u16 As[128 * 32];
  __shared__ __align__(16) u16 Bs[128 * 32];
  __shared__ float smu[128], srs[128];
  int id = blockIdx.x, tid = threadIdx.x;
  int wv = tid >> 6, lane = tid & 63;
  int srow = wv * 16 + (lane >> 2);
  int scol = (lane & 3) * 8;
  int wm = (wv & 1) * 64, wn = (wv >> 1) * 64;
  int fr = lane & 15, fq = (lane >> 4) * 8;
  f4 acc[4][4];
  #pragma unroll
  for (int mi = 0; mi < 4; mi++)
    #pragma unroll
    for (int ni = 0; ni < 4; ni++) acc[mi][ni] = f4{0.f, 0.f, 0.f, 0.f};
  int er = (lane >> 4) * 4;
  int ec = lane & 15;

  if (id < 2048) {
    // ---- kv path ----
    int xg = id & 7, t = id >> 3;
    int mtile = xg * 32 + (t >> 3);
    int n0 = (t & 7) * 128;
    int batch = mtile >> 4;
    int ml = (mtile & 15) * 128;
    if (ml >= cnt[batch]) return;
    size_t arow = (size_t)batch * NN + ml;
    const u16* gA0 = xcomp + (arow + srow) * 1024 + scol;
    const u16* gA1 = xcomp + (arow + 64 + srow) * 1024 + scol;
    const u16* gB0 = WkvTf + (size_t)(n0 + srow) * 1024 + scol;
    const u16* gB1 = WkvTf + (size_t)(n0 + 64 + srow) * 1024 + scol;
    u16* lA0 = &As[srow * 32 + scol];
    u16* lA1 = &As[(64 + srow) * 32 + scol];
    u16* lB0 = &Bs[srow * 32 + scol];
    u16* lB1 = &Bs[(64 + srow) * 32 + scol];
    for (int k0 = 0; k0 < 1024; k0 += 32) {
      gl_lds16(gA0 + k0, lA0);
      gl_lds16(gA1 + k0, lA1);
      gl_lds16(gB0 + k0, lB0);
      gl_lds16(gB1 + k0, lB1);
      __syncthreads();
      short8 af[4], bfr[4];
      #pragma unroll
      for (int mi = 0; mi < 4; mi++) af[mi] = *(const short8*)&As[(wm + mi*16 + fr) * 32 + fq];
      #pragma unroll
      for (int ni = 0; ni < 4; ni++) bfr[ni] = *(const short8*)&Bs[(wn + ni*16 + fr) * 32 + fq];
      #pragma unroll
      for (int mi = 0; mi < 4; mi++)
        #pragma unroll
        for (int ni = 0; ni < 4; ni++)
          acc[mi][ni] = __builtin_amdgcn_mfma_f32_16x16x32_bf16(af[mi], bfr[ni], acc[mi][ni], 0, 0, 0);
      __syncthreads();
    }
    #pragma unroll
    for (int mi = 0; mi < 4; mi++) {
      #pragma unroll
      for (int ni = 0; ni < 4; ni++) {
        int col = n0 + wn + ni*16 + ec;
        float bv = biaskv[col];
        int rbase = ml + wm + mi*16 + er;
        if (col < 512) {
          #pragma unroll
          for (int r = 0; r < 4; r++)
            kx[((size_t)batch * NN + rbase + r) * 512 + col] = f2bf(acc[mi][ni][r] + bv);
        } else {
          union { u16 u[4]; ushort4 s; } pk;
          #pragma unroll
          for (int r = 0; r < 4; r++) pk.u[r] = f2bf(acc[mi][ni][r] + bv);
          *(ushort4*)&vxT[((size_t)batch * 512 + (col - 512)) * NN + rbase] = pk.s;
        }
      }
    }
  } else {
    // ---- latent qkv path (LN fused via stats; affine folded into WqkvT/biasqkv) ----
    int l = id - 2048;
    int m0 = (l / 12) * 128, n0 = (l % 12) * 128;
    for (int rr = 0; rr < 32; rr++) {
      int row = m0 + wv * 32 + rr;
      const float4* rp = (const float4*)(lat + (size_t)row * 1024);
      float s = 0.f, s2 = 0.f;
      #pragma unroll
      for (int it = 0; it < 4; it++) {
        float4 v = rp[it * 64 + lane];
        s += v.x + v.y + v.z + v.w;
        s2 += v.x*v.x + v.y*v.y + v.z*v.z + v.w*v.w;
      }
      #pragma unroll
      for (int off = 32; off >= 1; off >>= 1) {
        s  += __shfl_xor(s, off, 64);
        s2 += __shfl_xor(s2, off, 64);
      }
      if (lane == 0) {
        float mu = s * (1.f/1024.f);
        float var = s2 * (1.f/1024.f) - mu * mu;
        smu[wv*32 + rr] = mu;
        srs[wv*32 + rr] = rsqrtf(var + 1e-5f);
      }
    }
    __syncthreads();
    const u16* gB0 = WqkvT + (size_t)(n0 + srow) * 1024 + scol;
    const u16* gB1 = WqkvT + (size_t)(n0 + 64 + srow) * 1024 + scol;
    u16* lB0 = &Bs[srow * 32 + scol];
    u16* lB1 = &Bs[(64 + srow) * 32 + scol];
    for (int k0 = 0; k0 < 1024; k0 += 32) {
      #pragma unroll
      for (int cc = 0; cc < 2; cc++) {
        int ch = tid * 2 + cc;
        int row = ch >> 2, c8 = (ch & 3) * 8;
        const float4* lp = (const float4*)(lat + (size_t)(m0 + row) * 1024 + k0 + c8);
        float4 a = lp[0], b = lp[1];
        float mu = smu[row], rs = srs[row];
        float v[8] = {(a.x-mu)*rs, (a.y-mu)*rs, (a.z-mu)*rs, (a.w-mu)*rs,
                      (b.x-mu)*rs, (b.y-mu)*rs, (b.z-mu)*rs, (b.w-mu)*rs};
        pack8(v, &As[row * 32 + c8]);
      }
      gl_lds16(gB0 + k0, lB0);
      gl_lds16(gB1 + k0, lB1);
      __syncthreads();
      short8 af[4], bfr[4];
      #pragma unroll
      for (int mi = 0; mi < 4; mi++) af[mi] = *(const short8*)&As[(wm + mi*16 + fr) * 32 + fq];
      #pragma unroll
      for (int ni = 0; ni < 4; ni++) bfr[ni] = *(const short8*)&Bs[(wn + ni*16 + fr) * 32 + fq];
      #pragma unroll
      for (int mi = 0; mi < 4; mi++)
        #pragma unroll
        for (int ni = 0; ni < 4; ni++)
          acc[mi][ni] = __builtin_amdgcn_mfma_f32_16x16x32_bf16(af[mi], bfr[ni], acc[mi][ni], 0, 0, 0);
      __syncthreads();
    }
    #pragma unroll
    for (int mi = 0; mi < 4; mi++) {
      #pragma unroll
      for (int ni = 0; ni < 4; ni++) {
        int col = n0 + wn + ni*16 + ec;
        float bv = biasqkv[col];
        int rbase = m0 + wm + mi*16 + er;
        if (col < 1024) {
          #pragma unroll
          for (int r = 0; r < 4; r++)
            qk[(size_t)(rbase + r) * 1024 + col] = f2bf(acc[mi][ni][r] + bv);
        } else {
          int b = rbase >> 6, qrow = rbase & 63;
          union { u16 u[4]; ushort4 s; } pk;
          #pragma unroll
          for (int r = 0; r < 4; r++) pk.u[r] = f2bf(acc[mi][ni][r] + bv);
          *(ushort4*)&vlatT[((size_t)b * 512 + (col - 1024)) * 64 + qrow] = pk.s;
        }
      }
    }
  }
}

// ---------------- flash attention, split over keys: 2 blocks per (b,h) ----------------
__global__ __launch_bounds__(256) void attn_part_k(const u16* __restrict__ qk,
    const u16* __restrict__ vlatT, const u16* __restrict__ kx, const u16* __restrict__ vxT,
    const int* __restrict__ cnt, float* __restrict__ opart, float* __restrict__ mlpart) {
  int id = blockIdx.x;          // 256 = b(16) x h(8) x half(2)
  int b = id >> 4;
  int h = (id >> 1) & 7;
  int half = id & 1;
  int tid = threadIdx.x;
  int wv = tid >> 6, lane = tid & 63;
  int fr = lane & 15, fq8 = (lane >> 4) * 8;
  int c = cnt[b];
  int nt = (c + 63) >> 6;
  int T = nt + 1;
  int t0 = half ? (T >> 1) : 0;
  int t1 = half ? T : (T >> 1);

  __shared__ __align__(16) u16 ks[64 * 72];
  __shared__ __align__(16) u16 vs[64 * 72];
  __shared__ __align__(16) u16 ps[4][16 * 72];
  __shared__ float smask[64];

  const u16* qp = qk + (size_t)(b * LL + wv * 16 + fr) * 1024 + h * DHD;
  short8 aq0 = *(const short8*)(qp + fq8);
  short8 aq1 = *(const short8*)(qp + 32 + fq8);

  float m_i[4], l_i[4];
  f4 o[4];
  #pragma unroll
  for (int r = 0; r < 4; r++) { m_i[r] = -1e30f; l_i[r] = 0.f; }
  #pragma unroll
  for (int dt = 0; dt < 4; dt++) o[dt] = f4{0.f, 0.f, 0.f, 0.f};

  const float scale = 0.125f;

  for (int t = t0; t < t1; t++) {
    bool isLat = (t == nt);
    const u16 *srck, *srcv;
    int strk, strv;
    if (isLat) {
      srck = qk + (size_t)(b * LL) * 1024 + 512 + h * DHD; strk = 1024;
      srcv = vlatT + (size_t)(b * 512 + h * DHD) * 64;     strv = 64;
    } else {
      srck = kx + ((size_t)b * NN + t * 64) * 512 + h * DHD; strk = 512;
      srcv = vxT + ((size_t)b * 512 + h * DHD) * NN + t * 64; strv = NN;
    }
    __syncthreads();
    #pragma unroll
    for (int it = 0; it < 2; it++) {
      int cid = it * 256 + tid;
      int kr = cid >> 3, c8 = (cid & 7) * 8;
      *(int4*)&ks[kr * 72 + c8] = *(const int4*)(srck + (size_t)kr * strk + c8);
      *(int4*)&vs[kr * 72 + c8] = *(const int4*)(srcv + (size_t)kr * strv + c8);
    }
    if (tid < 64)
      smask[tid] = (isLat || (t * 64 + tid < c)) ? 0.f : -1e30f;
    __syncthreads();

    f4 sim[4];
    #pragma unroll
    for (int ct = 0; ct < 4; ct++) {
      short8 b0 = *(const short8*)&ks[(ct*16 + fr) * 72 + fq8];
      short8 b1 = *(const short8*)&ks[(ct*16 + fr) * 72 + 32 + fq8];
      f4 s = f4{0.f, 0.f, 0.f, 0.f};
      s = __builtin_amdgcn_mfma_f32_16x16x32_bf16(aq0, b0, s, 0, 0, 0);
      s = __builtin_amdgcn_mfma_f32_16x16x32_bf16(aq1, b1, s, 0, 0, 0);
      float mk = smask[ct*16 + fr];
      #pragma unroll
      for (int r = 0; r < 4; r++) s[r] = s[r] * scale + mk;
      sim[ct] = s;
    }
    float mnew[4], alpha[4], p[4][4];
    #pragma unroll
    for (int r = 0; r < 4; r++) {
      float mx = fmaxf(fmaxf(sim[0][r], sim[1][r]), fmaxf(sim[2][r], sim[3][r]));
      #pragma unroll
      for (int off = 8; off >= 1; off >>= 1) mx = fmaxf(mx, __shfl_xor(mx, off, 16));
      mnew[r] = fmaxf(m_i[r], mx);
      alpha[r] = __expf(m_i[r] - mnew[r]);
      m_i[r] = mnew[r];
      float ssum = 0.f;
      #pragma unroll
      for (int ct = 0; ct < 4; ct++) { float e = __expf(sim[ct][r] - mnew[r]); p[ct][r] = e; ssum += e; }
      #pragma unroll
      for (int off = 8; off >= 1; off >>= 1) ssum += __shfl_xor(ssum, off, 16);
      l_i[r] = l_i[r] * alpha[r] + ssum;
    }
    #pragma unroll
    for (int ct = 0; ct < 4; ct++)
      #pragma unroll
      for (int r = 0; r < 4; r++)
        ps[wv][((lane>>4)*4 + r) * 72 + ct*16 + fr] = f2bf(p[ct][r]);
    #pragma unroll
    for (int dt = 0; dt < 4; dt++)
      #pragma unroll
      for (int r = 0; r < 4; r++) o[dt][r] *= alpha[r];
    short8 pa0 = *(const short8*)&ps[wv][fr * 72 + fq8];
    short8 pa1 = *(const short8*)&ps[wv][fr * 72 + 32 + fq8];
    #pragma unroll
    for (int dt = 0; dt < 4; dt++) {
      short8 bv0 = *(const short8*)&vs[(dt*16 + fr) * 72 + fq8];
      short8 bv1 = *(const short8*)&vs[(dt*16 + fr) * 72 + 32 + fq8];
      o[dt] = __builtin_amdgcn_mfma_f32_16x16x32_bf16(pa0, bv0, o[dt], 0, 0, 0);
      o[dt] = __builtin_amdgcn_mfma_f32_16x16x32_bf16(pa1, bv1, o[dt], 0, 0, 0);
    }
  }
  #pragma unroll
  for (int dt = 0; dt < 4; dt++)
    #pragma unroll
    for (int r = 0; r < 4; r++) {
      int row = wv * 16 + (lane>>4)*4 + r;
      int col = dt*16 + fr;
      opart[((size_t)id * 64 + row) * 64 + col] = o[dt][r];
    }
  if (fr == 0) {
    #pragma unroll
    for (int r = 0; r < 4; r++) {
      int row = wv * 16 + (lane>>4)*4 + r;
      mlpart[id * 128 + row * 2]     = m_i[r];
      mlpart[id * 128 + row * 2 + 1] = l_i[r];
    }
  }
}

// ---------------- Wo GEMM split-K with fused attention combine (A built from opart/ml) -------
__global__ __launch_bounds__(256) void gemm_wo_k(const float* __restrict__ opart,
    const float* __restrict__ mlpart, const u16* __restrict__ WoT, float* __restrict__ lat) {
  __shared__ __align__(16) u16 As[128 * 32];
  __shared__ __align__(16) u16 Bs[128 * 32];
  __shared__ float f0s[128][2], f1s[128][2];
  int tid = threadIdx.x;
  int wv = tid >> 6, lane = tid & 63;
  int m0 = blockIdx.y * 128, n0 = blockIdx.x * 128, kb = blockIdx.z * 128;
  int h0 = kb >> 6;
  {
    int row = tid >> 1, hh = tid & 1;
    int grow = m0 + row;
    int gb = grow >> 6, qrow = grow & 63;
    int id0 = (gb * 8 + h0 + hh) * 2;
    float ma = mlpart[id0 * 128 + qrow * 2],       la = mlpart[id0 * 128 + qrow * 2 + 1];
    float mb = mlpart[(id0 + 1) * 128 + qrow * 2], lb = mlpart[(id0 + 1) * 128 + qrow * 2 + 1];
    float mm = fmaxf(ma, mb);
    float a0 = __expf(ma - mm), a1 = __expf(mb - mm);
    float rl = 1.f / (la * a0 + lb * a1);
    f0s[row][hh] = a0 * rl;
    f1s[row][hh] = a1 * rl;
  }
  __syncthreads();
  int srow = wv * 16 + (lane >> 2);
  int scol = (lane & 3) * 8;
  const u16* gB0 = WoT + (size_t)(n0 + srow) * 512 + kb + scol;
  const u16* gB1 = WoT + (size_t)(n0 + 64 + srow) * 512 + kb + scol;
  u16* lB0 = &Bs[srow * 32 + scol];
  u16* lB1 = &Bs[(64 + srow) * 32 + scol];
  int wm = (wv & 1) * 64, wn = (wv >> 1) * 64;
  int fr = lane & 15, fq = (lane >> 4) * 8;
  f4 acc[4][4];
  #pragma unroll
  for (int mi = 0; mi < 4; mi++)
    #pragma unroll
    for (int ni = 0; ni < 4; ni++) acc[mi][ni] = f4{0.f, 0.f, 0.f, 0.f};

  for (int ki = 0; ki < 4; ki++) {
    int k0 = kb + ki * 32;
    #pragma unroll
    for (int cc = 0; cc < 2; cc++) {
      int ch = tid * 2 + cc;
      int row = ch >> 2, c8 = (ch & 3) * 8;
      int koff = k0 + c8;
      int hh = (koff - kb) >> 6;
      int kc = koff & 63;
      int grow = m0 + row;
      int gb = grow >> 6, qrow = grow & 63;
      int id0 = (gb * 8 + h0 + hh) * 2;
      const float4* p0 = (const float4*)(opart + ((size_t)id0 * 64 + qrow) * 64 + kc);
      const float4* p1 = (const float4*)(opart + ((size_t)(id0 + 1) * 64 + qrow) * 64 + kc);
      float4 x0 = p0[0], x1 = p0[1], y0 = p1[0], y1 = p1[1];
      float f0 = f0s[row][hh], f1 = f1s[row][hh];
      float v[8] = {x0.x*f0 + y0.x*f1, x0.y*f0 + y0.y*f1, x0.z*f0 + y0.z*f1, x0.w*f0 + y0.w*f1,
                    x1.x*f0 + y1.x*f1, x1.y*f0 + y1.y*f1, x1.z*f0 + y1.z*f1, x1.w*f0 + y1.w*f1};
      pack8(v, &As[row * 32 + c8]);
    }
    gl_lds16(gB0 + ki * 32, lB0);
    gl_lds16(gB1 + ki * 32, lB1);
    __syncthreads();
    short8 af[4], bfr[4];
    #pragma unroll
    for (int mi = 0; mi < 4; mi++) af[mi] = *(const short8*)&As[(wm + mi*16 + fr) * 32 + fq];
    #pragma unroll
    for (int ni = 0; ni < 4; ni++) bfr[ni] = *(const short8*)&Bs[(wn + ni*16 + fr) * 32 + fq];
    #pragma unroll
    for (int mi = 0; mi < 4; mi++)
      #pragma unroll
      for (int ni = 0; ni < 4; ni++)
        acc[mi][ni] = __builtin_amdgcn_mfma_f32_16x16x32_bf16(af[mi], bfr[ni], acc[mi][ni], 0, 0, 0);
    __syncthreads();
  }
  int er = (lane >> 4) * 4;
  int ec = lane & 15;
  #pragma unroll
  for (int mi = 0; mi < 4; mi++)
    #pragma unroll
    for (int ni = 0; ni < 4; ni++) {
      int col = n0 + wn + ni*16 + ec;
      #pragma unroll
      for (int r = 0; r < 4; r++) {
        int row = m0 + wm + mi*16 + er + r;
        atomicAdd(&lat[(size_t)row * 1024 + col], acc[mi][ni][r]);
      }
    }
}

// ---------------- W1 GEMM with fused FF-LN (stats in-block; affine folded) + gelu ------------
__global__ __launch_bounds__(256) void gemm_gelu_ln_k(const float* __restrict__ lat,
    const u16* __restrict__ W1T, const float* __restrict__ bias1, u16* __restrict__ hf) {
  __shared__ __align__(16) u16 As[128 * 32];
  __shared__ __align__(16) u16 Bs[128 * 32];
  __shared__ float smu[128], srs[128];
  int tid = threadIdx.x;
  int wv = tid >> 6, lane = tid & 63;
  int m0 = blockIdx.y * 128, n0 = blockIdx.x * 128;
  for (int rr = 0; rr < 32; rr++) {
    int row = m0 + wv * 32 + rr;
    const float4* rp = (const float4*)(lat + (size_t)row * 1024);
    float s = 0.f, s2 = 0.f;
    #pragma unroll
    for (int it = 0; it < 4; it++) {
      float4 v = rp[it * 64 + lane];
      s += v.x + v.y + v.z + v.w;
      s2 += v.x*v.x + v.y*v.y + v.z*v.z + v.w*v.w;
    }
    #pragma unroll
    for (int off = 32; off >= 1; off >>= 1) {
      s  += __shfl_xor(s, off, 64);
      s2 += __shfl_xor(s2, off, 64);
    }
    if (lane == 0) {
      float mu = s * (1.f/1024.f);
      float var = s2 * (1.f/1024.f) - mu * mu;
      smu[wv*32 + rr] = mu;
      srs[wv*32 + rr] = rsqrtf(var + 1e-5f);
    }
  }
  __syncthreads();
  int srow = wv * 16 + (lane >> 2);
  int scol = (lane & 3) * 8;
  const u16* gB0 = W1T + (size_t)(n0 + srow) * 1024 + scol;
  const u16* gB1 = W1T + (size_t)(n0 + 64 + srow) * 1024 + scol;
  u16* lB0 = &Bs[srow * 32 + scol];
  u16* lB1 = &Bs[(64 + srow) * 32 + scol];
  int wm = (wv & 1) * 64, wn = (wv >> 1) * 64;
  int fr = lane & 15, fq = (lane >> 4) * 8;
  f4 acc[4][4];
  #pragma unroll
  for (int mi = 0; mi < 4; mi++)
    #pragma unroll
    for (int ni = 0; ni < 4; ni++) acc[mi][ni] = f4{0.f, 0.f, 0.f, 0.f};

  for (int k0 = 0; k0 < 1024; k0 += 32) {
    #pragma unroll
    for (int cc = 0; cc < 2; cc++) {
      int ch = tid * 2 + cc;
      int row = ch >> 2, c8 = (ch & 3) * 8;
      const float4* lp = (const float4*)(lat + (size_t)(m0 + row) * 1024 + k0 + c8);
      float4 a = lp[0], b = lp[1];
      float mu = smu[row], rs = srs[row];
      float v[8] = {(a.x-mu)*rs, (a.y-mu)*rs, (a.z-mu)*rs, (a.w-mu)*rs,
                    (b.x-mu)*rs, (b.y-mu)*rs, (b.z-mu)*rs, (b.w-mu)*rs};
      pack8(v, &As[row * 32 + c8]);
    }
    gl_lds16(gB0 + k0, lB0);
    gl_lds16(gB1 + k0, lB1);
    __syncthreads();
    short8 af[4], bfr[4];
    #pragma unroll
    for (int mi = 0; mi < 4; mi++) af[mi] = *(const short8*)&As[(wm + mi*16 + fr) * 32 + fq];
    #pragma unroll
    for (int ni = 0; ni < 4; ni++) bfr[ni] = *(const short8*)&Bs[(wn + ni*16 + fr) * 32 + fq];
    #pragma unroll
    for (int mi = 0; mi < 4; mi++)
      #pragma unroll
      for (int ni = 0; ni < 4; ni++)
        acc[mi][ni] = __builtin_amdgcn_mfma_f32_16x16x32_bf16(af[mi], bfr[ni], acc[mi][ni], 0, 0, 0);
    __syncthreads();
  }
  int er = (lane >> 4) * 4;
  int ec = lane & 15;
  #pragma unroll
  for (int mi = 0; mi < 4; mi++)
    #pragma unroll
    for (int ni = 0; ni < 4; ni++) {
      int col = n0 + wn + ni*16 + ec;
      float bv = bias1[col];
      #pragma unroll
      for (int r = 0; r < 4; r++) {
        int row = m0 + wm + mi*16 + er + r;
        float v = acc[mi][ni][r] + bv;
        v = 0.5f * v * (1.f + erff(v * 0.70710678118654752f));
        hf[(size_t)row * 4096 + col] = f2bf(v);
      }
    }
}

// ---------------- split-K GEMM (W2), fp32 atomicAdd epilogue (lat pre-holds residual) --------
__global__ __launch_bounds__(256) void gemmsk_k(const u16* __restrict__ A, const u16* __restrict__ Bm,
    float* __restrict__ C, int M, int N, int K, int Kc) {
  __shared__ __align__(16) u16 As[128 * 32];
  __shared__ __align__(16) u16 Bs[128 * 32];
  int tid = threadIdx.x;
  int wv = tid >> 6, lane = tid & 63;
  int m0 = blockIdx.y * 128, n0 = blockIdx.x * 128;
  int kb = blockIdx.z * Kc;
  int srow = wv * 16 + (lane >> 2);
  int scol = (lane & 3) * 8;
  const u16* gA0 = A + (size_t)(m0 + srow) * K + kb + scol;
  const u16* gA1 = A + (size_t)(m0 + 64 + srow) * K + kb + scol;
  const u16* gB0 = Bm + (size_t)(n0 + srow) * K + kb + scol;
  const u16* gB1 = Bm + (size_t)(n0 + 64 + srow) * K + kb + scol;
  u16* lA0 = &As[srow * 32 + scol];
  u16* lA1 = &As[(64 + srow) * 32 + scol];
  u16* lB0 = &Bs[srow * 32 + scol];
  u16* lB1 = &Bs[(64 + srow) * 32 + scol];
  int wm = (wv & 1) * 64, wn = (wv >> 1) * 64;
  int fr = lane & 15, fq = (lane >> 4) * 8;
  f4 acc[4][4];
  #pragma unroll
  for (int mi = 0; mi < 4; mi++)
    #pragma unroll
    for (int ni = 0; ni < 4; ni++) acc[mi][ni] = f4{0.f, 0.f, 0.f, 0.f};

  for (int k0 = 0; k0 < Kc; k0 += 32) {
    gl_lds16(gA0 + k0, lA0);
    gl_lds16(gA1 + k0, lA1);
    gl_lds16(gB0 + k0, lB0);
    gl_lds16(gB1 + k0, lB1);
    __syncthreads();
    short8 af[4], bfr[4];
    #pragma unroll
    for (int mi = 0; mi < 4; mi++) af[mi] = *(const short8*)&As[(wm + mi*16 + fr) * 32 + fq];
    #pragma unroll
    for (int ni = 0; ni < 4; ni++) bfr[ni] = *(const short8*)&Bs[(wn + ni*16 + fr) * 32 + fq];
    #pragma unroll
    for (int mi = 0; mi < 4; mi++)
      #pragma unroll
      for (int ni = 0; ni < 4; ni++)
        acc[mi][ni] = __builtin_amdgcn_mfma_f32_16x16x32_bf16(af[mi], bfr[ni], acc[mi][ni], 0, 0, 0);
    __syncthreads();
  }
  int er = (lane >> 4) * 4;
  int ec = lane & 15;
  #pragma unroll
  for (int mi = 0; mi < 4; mi++)
    #pragma unroll
    for (int ni = 0; ni < 4; ni++) {
      int col = n0 + wn + ni*16 + ec;
      #pragma unroll
      for (int r = 0; r < 4; r++) {
        int row = m0 + wm + mi*16 + er + r;
        atomicAdd(&C[(size_t)row * N + col], acc[mi][ni][r]);
      }
    }
}

extern "C" void kernel_launch(void* const* d_in, const int* in_sizes, int n_in,
                              void* d_out, int out_size, void* d_ws, size_t ws_size,
                              hipStream_t stream) {
  (void)in_sizes; (void)n_in; (void)out_size; (void)ws_size;
  const float* x       = (const float*)d_in[0];
  const int*   mask    = (const int*)d_in[1];
  const float* latents = (const float*)d_in[2];
  const float* ln_m_w  = (const float*)d_in[3];
  const float* ln_m_b  = (const float*)d_in[4];
  const float* ln_l_w  = (const float*)d_in[5];
  const float* ln_l_b  = (const float*)d_in[6];
  const float* Wq      = (const float*)d_in[7];
  const float* Wkv     = (const float*)d_in[8];
  const float* Wo      = (const float*)d_in[9];
  const float* ff_ln_w = (const float*)d_in[10];
  const float* ff_ln_b = (const float*)d_in[11];
  const float* W1      = (const float*)d_in[12];
  const float* W2      = (const float*)d_in[13];
  const float* norm_w  = (const float*)d_in[14];
  const float* norm_b  = (const float*)d_in[15];
  float* out = (float*)d_out;

  char* ws = (char*)d_ws;
  size_t off = 0;
  auto alloc = [&](size_t bytes) -> void* {
    void* p = ws + off; off += (bytes + 255) & ~(size_t)255; return p;
  };
  u16* xcomp = (u16*)alloc((size_t)BB * NN * 1024 * 2);
  u16* kx    = (u16*)alloc((size_t)BB * NN * 512 * 2);
  u16* vxT   = (u16*)alloc((size_t)BB * 512 * NN * 2);
  int* idxb  = (int*)alloc((size_t)BB * NN * 4);
  int* cnt   = (int*)alloc(64);
  float* lat = (float*)alloc((size_t)1024 * 1024 * 4);
  u16* qk    = (u16*)alloc((size_t)1024 * 1024 * 2);
  u16* vlatT = (u16*)alloc((size_t)BB * 512 * 64 * 2);
  u16* hf    = (u16*)alloc((size_t)1024 * 4096 * 2);
  float* opart  = (float*)alloc((size_t)256 * 64 * 64 * 4);
  float* mlpart = (float*)alloc((size_t)256 * 128 * 4);
  u16* WqkvT = (u16*)alloc((size_t)DEPTHC * 1536 * 1024 * 2);
  u16* WkvTf = (u16*)alloc((size_t)DEPTHC * 1024 * 1024 * 2);
  u16* WoT   = (u16*)alloc((size_t)DEPTHC * 1024 * 512 * 2);
  u16* W1T   = (u16*)alloc((size_t)DEPTHC * 4096 * 1024 * 2);
  u16* W2T   = (u16*)alloc((size_t)DEPTHC * 1024 * 4096 * 2);
  const int nbias = DEPTHC * (1536 + 1024 + 4096);
  float* biasall = (float*)alloc((size_t)nbias * 4);

  pre0_k<<<16 + 1024 + 40, 256, 0, stream>>>(mask, idxb, cnt, latents, lat, biasall, nbias);
  ln_gather_k<<<dim3(2048, 16), 256, 0, stream>>>(x, idxb, cnt, xcomp);
  transpall_k<<<DEPTHC * 2560, 256, 0, stream>>>(
      Wq, Wkv, Wo, W1, W2, ln_l_w, ln_l_b, ln_m_w, ln_m_b, ff_ln_w, ff_ln_b,
      WqkvT, WkvTf, WoT, W1T, W2T, biasall);

  for (int i = 0; i < DEPTHC; i++) {
    float* biasqkv = biasall + i * 1536;
    float* biaskv  = biasall + DEPTHC*1536 + i * 1024;
    float* bias1   = biasall + DEPTHC*1536 + DEPTHC*1024 + i * 4096;
    gemm_fused_k<<<2144, 256, 0, stream>>>(
        xcomp, WkvTf + (size_t)i*1024*1024, biaskv, kx, vxT, cnt,
        lat, WqkvT + (size_t)i*1536*1024, biasqkv, qk, vlatT);
    attn_part_k<<<256, 256, 0, stream>>>(qk, vlatT, kx, vxT, cnt, opart, mlpart);
    gemm_wo_k<<<dim3(8, 8, 4), 256, 0, stream>>>(opart, mlpart, WoT + (size_t)i*1024*512, lat);
    gemm_gelu_ln_k<<<dim3(32, 8), 256, 0, stream>>>(lat, W1T + (size_t)i*4096*1024, bias1, hf);
    gemmsk_k<<<dim3(8, 8, 4), 256, 0, stream>>>(hf, W2T + (size_t)i*1024*4096, lat, 1024, 1024, 4096, 1024);
  }
  ln_final_k<<<1024, 256, 0, stream>>>(lat, norm_w, norm_b, out);
}